// Round 3
// baseline (2916.472 us; speedup 1.0000x reference)
//
#include <hip/hip_runtime.h>
#include <math.h>

#define BATCH 8192
#define NB 2          // batch elements per lane; 8192/2 = 4096 waves = 4 waves/SIMD
#define NCOL 512
#define MNODE 256

// ---------------------------------------------------------------------------
// Fused per-node 2x2 complex matrix: N = R * diag(e^{i th},1) * L * diag(e^{i ph},1)
// pp[2n+0] = (n11r, n11i, n12r, n12i); pp[2n+1] = (n21r, n21i, n22r, n22i)
// Apply: top' = n11*vt + n12*vb ; bot' = n21*vt + n22*vb   (verified rounds 1-2)
// ---------------------------------------------------------------------------
__global__ __launch_bounds__(256) void precomp_kernel(
    const float* __restrict__ thetas, const float* __restrict__ phis,
    const float* __restrict__ bse, const float* __restrict__ lse,
    float4* __restrict__ pp) {
  int n = blockIdx.x * 256 + threadIdx.x;
  float th = thetas[n], ph = phis[n];
  float e0 = bse[2 * n + 0], e1 = bse[2 * n + 1];
  float l0 = lse[2 * n + 0], l1 = lse[2 * n + 1];
  const float K = 0.16609640474436813f;  // log2(10)/20
  float ins0 = exp2f(l0 * K), ins1 = exp2f(l1 * K);
  const float PI4 = 0.7853981633974483f;
  float s0, c0, s1, c1, sp, cp, st, ct;
  sincosf(PI4 + e0, &s0, &c0);
  sincosf(PI4 + e1, &s1, &c1);
  sincosf(ph, &sp, &cp);
  sincosf(th, &st, &ct);
  float AL = ins0 * s0, C1L = c0, C2L = ins0 * c0, SL = s0;
  float AR = ins1 * s1, C1R = c1, C2R = ins1 * c1, SR = s1;
  float a11r = AL * cp,   a11i = AL * sp;
  float a12r = 0.f,       a12i = C1L;
  float a21r = -C2L * sp, a21i = C2L * cp;
  float a22r = SL,        a22i = 0.f;
  float b11r = a11r * ct - a11i * st, b11i = a11r * st + a11i * ct;
  float b12r = a12r * ct - a12i * st, b12i = a12r * st + a12i * ct;
  float n11r = AR * b11r - C1R * a21i;
  float n11i = AR * b11i + C1R * a21r;
  float n12r = AR * b12r - C1R * a22i;
  float n12i = AR * b12i + C1R * a22r;
  float n21r = -C2R * b11i + SR * a21r;
  float n21i =  C2R * b11r + SR * a21i;
  float n22r = -C2R * b12i + SR * a22r;
  float n22i =  C2R * b12r + SR * a22i;
  pp[2 * n + 0] = make_float4(n11r, n11i, n12r, n12i);
  pp[2 * n + 1] = make_float4(n21r, n21i, n22r, n22i);
}

// General complex 2x2 apply: 16 FMA-class ops.
__device__ __forceinline__ void proc_pair(float& vtr, float& vti, float& vbr, float& vbi,
                                          const float4 q0, const float4 q1) {
  float tr = q0.x * vtr - q0.y * vti + q0.z * vbr - q0.w * vbi;
  float ti = q0.x * vti + q0.y * vtr + q0.z * vbi + q0.w * vbr;
  float br = q1.x * vtr - q1.y * vti + q1.z * vbr - q1.w * vbi;
  float bi = q1.x * vti + q1.y * vtr + q1.z * vbi + q1.w * vbr;
  vtr = tr; vti = ti; vbr = br; vbi = bi;
}

// ---------------------------------------------------------------------------
// Mesh sweep. Lane l owns rows 8l..8l+7 for NB batch cols (32 VGPRs state).
// Even cols: 4 in-lane pairs (node 4l+k). Odd cols: 3 in-lane pairs + the
// cross pair computed HALF-per-lane with only up-front shuffles:
//   - lane l computes the TOP half of node 4l+3 (own row7 + shfl_down(row0))
//   - lane l computes the BOTTOM half of node 4(l-1)+3 (shfl_up(old row7) +
//     own row0), using the neighbor's q1 matrix row obtained by shfl_up.
// No dependent shuffle-after-compute round trip. Lane63 top-write suppressed
// (masked node 255); lane0 bottom-write suppressed (node -1). Semantics
// validated against reference in rounds 1-2.
// ---------------------------------------------------------------------------
__global__ __launch_bounds__(256, 4) void mesh_kernel(
    const float* __restrict__ x, const float* __restrict__ gammas,
    const float4* __restrict__ pp, float* __restrict__ out) {
  const int lane = threadIdx.x & 63;
  const int wid = (blockIdx.x * blockDim.x + threadIdx.x) >> 6;
  const int b0 = wid * NB;

  float vr[8][NB], vi[8][NB];

  // init: v = x * exp(i*gamma)
#pragma unroll
  for (int r = 0; r < 8; ++r) {
    const int row = lane * 8 + r;
    float sg, cg;
    sincosf(gammas[row], &sg, &cg);
    float2 x0 = *(const float2*)(x + (size_t)row * BATCH + b0);
    float xb[NB] = {x0.x, x0.y};
#pragma unroll
    for (int q = 0; q < NB; ++q) {
      vr[r][q] = xb[q] * cg;
      vi[r][q] = xb[q] * sg;
    }
  }

  float4 pe[8], po[8];
  {
    const float4* p0 = pp + (size_t)(4 * lane) * 2;
#pragma unroll
    for (int i = 0; i < 8; ++i) pe[i] = p0[i];
  }

#pragma unroll 1
  for (int c = 0; c < NCOL; c += 2) {
    // prefetch odd column c+1 params
    {
      const float4* pO = pp + ((size_t)(c + 1) * MNODE + 4 * lane) * 2;
#pragma unroll
      for (int i = 0; i < 8; ++i) po[i] = pO[i];
    }

    // ---- even column c
#pragma unroll
    for (int k = 0; k < 4; ++k) {
#pragma unroll
      for (int q = 0; q < NB; ++q)
        proc_pair(vr[2 * k][q], vi[2 * k][q], vr[2 * k + 1][q], vi[2 * k + 1][q],
                  pe[2 * k], pe[2 * k + 1]);
    }

    // prefetch even column c+2 params (clamped; last-iter value unused)
    {
      const int c2 = (c + 2 < NCOL) ? (c + 2) : 0;
      const float4* pE = pp + ((size_t)c2 * MNODE + 4 * lane) * 2;
#pragma unroll
      for (int i = 0; i < 8; ++i) pe[i] = pE[i];
    }

    // neighbor's q1 matrix row for the cross pair (once per column)
    float4 pu1;
    pu1.x = __shfl_up(po[7].x, 1, 64);
    pu1.y = __shfl_up(po[7].y, 1, 64);
    pu1.z = __shfl_up(po[7].z, 1, 64);
    pu1.w = __shfl_up(po[7].w, 1, 64);

    // ---- odd column c+1: in-lane pairs (rows 1&2, 3&4, 5&6)
#pragma unroll
    for (int k = 0; k < 3; ++k) {
#pragma unroll
      for (int q = 0; q < NB; ++q)
        proc_pair(vr[2 * k + 1][q], vi[2 * k + 1][q], vr[2 * k + 2][q], vi[2 * k + 2][q],
                  po[2 * k], po[2 * k + 1]);
    }

    // ---- cross pair, half-per-lane, shuffles all up-front
#pragma unroll
    for (int q = 0; q < NB; ++q) {
      float br = __shfl_down(vr[0][q], 1, 64);   // neighbor's row0 (pre-update)
      float bi = __shfl_down(vi[0][q], 1, 64);
      float tu = __shfl_up(vr[7][q], 1, 64);     // left-neighbor's old row7
      float tv = __shfl_up(vi[7][q], 1, 64);
      // top half of own node 4l+3: new row7
      float nAr = po[6].x * vr[7][q] - po[6].y * vi[7][q] + po[6].z * br - po[6].w * bi;
      float nAi = po[6].x * vi[7][q] + po[6].y * vr[7][q] + po[6].z * bi + po[6].w * br;
      // bottom half of left-neighbor's node: new row0
      float nBr = pu1.x * tu - pu1.y * tv + pu1.z * vr[0][q] - pu1.w * vi[0][q];
      float nBi = pu1.x * tv + pu1.y * tu + pu1.z * vi[0][q] + pu1.w * vr[0][q];
      if (lane < 63) { vr[7][q] = nAr; vi[7][q] = nAi; }  // lane63 = masked node 255
      if (lane > 0)  { vr[0][q] = nBr; vi[0][q] = nBi; }  // lane0 row0 untouched
    }
  }

  // store: out[0]=real, out[1]=imag, each (512, 8192)
#pragma unroll
  for (int r = 0; r < 8; ++r) {
    const int row = lane * 8 + r;
    *(float2*)(out + (size_t)row * BATCH + b0) = make_float2(vr[r][0], vr[r][1]);
    *(float2*)(out + (size_t)(512 * BATCH) + (size_t)row * BATCH + b0) =
        make_float2(vi[r][0], vi[r][1]);
  }
}

extern "C" void kernel_launch(void* const* d_in, const int* in_sizes, int n_in,
                              void* d_out, int out_size, void* d_ws, size_t ws_size,
                              hipStream_t stream) {
  const float* x      = (const float*)d_in[0];
  const float* thetas = (const float*)d_in[1];
  const float* phis   = (const float*)d_in[2];
  const float* gammas = (const float*)d_in[3];
  const float* bse    = (const float*)d_in[4];
  const float* lse    = (const float*)d_in[5];
  // top/bottom/mask (d_in[6..8]) are deterministic (Clements mesh) — derived analytically.

  float4* pp = (float4*)d_ws;  // 131072 nodes * 2 float4 = 4 MB

  precomp_kernel<<<512, 256, 0, stream>>>(thetas, phis, bse, lse, pp);

  // 8192 / NB=2 = 4096 waves = 1024 blocks of 4 waves; 4 blocks/CU = 4 waves/SIMD
  mesh_kernel<<<1024, 256, 0, stream>>>(x, gammas, pp, (float*)d_out);
}

// Round 4
// 687.295 us; speedup vs baseline: 4.2434x; 4.2434x over previous
//
#include <hip/hip_runtime.h>
#include <math.h>

#define BATCH 8192
#define NROW 512
#define NCOL 512
#define MNODE 256
#define NB 2          // identity-columns per lane in compose

// ---------------------------------------------------------------------------
// Fused per-node 2x2 complex matrix: N = R * diag(e^{i th},1) * L * diag(e^{i ph},1)
// pp[2n+0] = (n11r, n11i, n12r, n12i); pp[2n+1] = (n21r, n21i, n22r, n22i)
// Apply: top' = n11*vt + n12*vb ; bot' = n21*vt + n22*vb   (verified rounds 1-3)
// ---------------------------------------------------------------------------
__global__ __launch_bounds__(256) void precomp_kernel(
    const float* __restrict__ thetas, const float* __restrict__ phis,
    const float* __restrict__ bse, const float* __restrict__ lse,
    float4* __restrict__ pp) {
  int n = blockIdx.x * 256 + threadIdx.x;
  float th = thetas[n], ph = phis[n];
  float e0 = bse[2 * n + 0], e1 = bse[2 * n + 1];
  float l0 = lse[2 * n + 0], l1 = lse[2 * n + 1];
  const float K = 0.16609640474436813f;  // log2(10)/20
  float ins0 = exp2f(l0 * K), ins1 = exp2f(l1 * K);
  const float PI4 = 0.7853981633974483f;
  float s0, c0, s1, c1, sp, cp, st, ct;
  sincosf(PI4 + e0, &s0, &c0);
  sincosf(PI4 + e1, &s1, &c1);
  sincosf(ph, &sp, &cp);
  sincosf(th, &st, &ct);
  float AL = ins0 * s0, C1L = c0, C2L = ins0 * c0, SL = s0;
  float AR = ins1 * s1, C1R = c1, C2R = ins1 * c1, SR = s1;
  float a11r = AL * cp,   a11i = AL * sp;
  float a12r = 0.f,       a12i = C1L;
  float a21r = -C2L * sp, a21i = C2L * cp;
  float a22r = SL,        a22i = 0.f;
  float b11r = a11r * ct - a11i * st, b11i = a11r * st + a11i * ct;
  float b12r = a12r * ct - a12i * st, b12i = a12r * st + a12i * ct;
  float n11r = AR * b11r - C1R * a21i;
  float n11i = AR * b11i + C1R * a21r;
  float n12r = AR * b12r - C1R * a22i;
  float n12i = AR * b12i + C1R * a22r;
  float n21r = -C2R * b11i + SR * a21r;
  float n21i =  C2R * b11r + SR * a21i;
  float n22r = -C2R * b12i + SR * a22r;
  float n22i =  C2R * b12r + SR * a22i;
  pp[2 * n + 0] = make_float4(n11r, n11i, n12r, n12i);
  pp[2 * n + 1] = make_float4(n21r, n21i, n22r, n22i);
}

// General complex 2x2 apply: 16 FMA-class ops.
__device__ __forceinline__ void proc_pair(float& vtr, float& vti, float& vbr, float& vbi,
                                          const float4 q0, const float4 q1) {
  float tr = q0.x * vtr - q0.y * vti + q0.z * vbr - q0.w * vbi;
  float ti = q0.x * vti + q0.y * vtr + q0.z * vbi + q0.w * vbr;
  float br = q1.x * vtr - q1.y * vti + q1.z * vbr - q1.w * vbi;
  float bi = q1.x * vti + q1.y * vtr + q1.z * vbi + q1.w * vbr;
  vtr = tr; vti = ti; vbr = br; vbi = bi;
}

// ---------------------------------------------------------------------------
// COMPOSE: run the mesh sweep on the gamma-phased identity to build the full
// transfer matrix T (complex 512x512). Since the mesh is linear in v and
// out = Mesh(diag(e^{ig}) x) = T x with T = Mesh(diag(e^{ig}) I).
// Lane l owns rows 8l..8l+7 for NB identity columns. Sweep structure
// (half-per-lane cross pair, up-front shuffles) verified in round 3.
// Output: A[1024x512] with rows 0..511 = T_re, rows 512..1023 = T_im.
// ---------------------------------------------------------------------------
__global__ __launch_bounds__(256, 2) void compose_kernel(
    const float* __restrict__ gammas, const float4* __restrict__ pp,
    float* __restrict__ T) {
  const int lane = threadIdx.x & 63;
  const int wid = (blockIdx.x * blockDim.x + threadIdx.x) >> 6;
  const int b0 = wid * NB;  // identity columns [b0, b0+NB)

  float vr[8][NB], vi[8][NB];

  // init: column j of diag(e^{i*gamma}) -> v[row][q] = (row==col) ? e^{ig_row} : 0
#pragma unroll
  for (int r = 0; r < 8; ++r) {
    const int row = lane * 8 + r;
    float sg, cg;
    sincosf(gammas[row], &sg, &cg);
#pragma unroll
    for (int q = 0; q < NB; ++q) {
      bool diag = (row == b0 + q);
      vr[r][q] = diag ? cg : 0.f;
      vi[r][q] = diag ? sg : 0.f;
    }
  }

  float4 pe[8], po[8];
  {
    const float4* p0 = pp + (size_t)(4 * lane) * 2;
#pragma unroll
    for (int i = 0; i < 8; ++i) pe[i] = p0[i];
  }

#pragma unroll 1
  for (int c = 0; c < NCOL; c += 2) {
    {
      const float4* pO = pp + ((size_t)(c + 1) * MNODE + 4 * lane) * 2;
#pragma unroll
      for (int i = 0; i < 8; ++i) po[i] = pO[i];
    }

    // even column c
#pragma unroll
    for (int k = 0; k < 4; ++k) {
#pragma unroll
      for (int q = 0; q < NB; ++q)
        proc_pair(vr[2 * k][q], vi[2 * k][q], vr[2 * k + 1][q], vi[2 * k + 1][q],
                  pe[2 * k], pe[2 * k + 1]);
    }

    {
      const int c2 = (c + 2 < NCOL) ? (c + 2) : 0;
      const float4* pE = pp + ((size_t)c2 * MNODE + 4 * lane) * 2;
#pragma unroll
      for (int i = 0; i < 8; ++i) pe[i] = pE[i];
    }

    float4 pu1;
    pu1.x = __shfl_up(po[7].x, 1, 64);
    pu1.y = __shfl_up(po[7].y, 1, 64);
    pu1.z = __shfl_up(po[7].z, 1, 64);
    pu1.w = __shfl_up(po[7].w, 1, 64);

    // odd column c+1: in-lane pairs (rows 1&2, 3&4, 5&6)
#pragma unroll
    for (int k = 0; k < 3; ++k) {
#pragma unroll
      for (int q = 0; q < NB; ++q)
        proc_pair(vr[2 * k + 1][q], vi[2 * k + 1][q], vr[2 * k + 2][q], vi[2 * k + 2][q],
                  po[2 * k], po[2 * k + 1]);
    }

    // cross pair, half-per-lane, shuffles all up-front (verified round 3)
#pragma unroll
    for (int q = 0; q < NB; ++q) {
      float br = __shfl_down(vr[0][q], 1, 64);
      float bi = __shfl_down(vi[0][q], 1, 64);
      float tu = __shfl_up(vr[7][q], 1, 64);
      float tv = __shfl_up(vi[7][q], 1, 64);
      float nAr = po[6].x * vr[7][q] - po[6].y * vi[7][q] + po[6].z * br - po[6].w * bi;
      float nAi = po[6].x * vi[7][q] + po[6].y * vr[7][q] + po[6].z * bi + po[6].w * br;
      float nBr = pu1.x * tu - pu1.y * tv + pu1.z * vr[0][q] - pu1.w * vi[0][q];
      float nBi = pu1.x * tv + pu1.y * tu + pu1.z * vi[0][q] + pu1.w * vr[0][q];
      if (lane < 63) { vr[7][q] = nAr; vi[7][q] = nAi; }
      if (lane > 0)  { vr[0][q] = nBr; vi[0][q] = nBi; }
    }
  }

  // store: T_re at rows 0..511, T_im at rows 512..1023 (A matrix, row-major K=512)
#pragma unroll
  for (int r = 0; r < 8; ++r) {
    const int row = lane * 8 + r;
    *(float2*)(T + (size_t)row * NROW + b0) = make_float2(vr[r][0], vr[r][1]);
    *(float2*)(T + (size_t)(NROW + row) * NROW + b0) = make_float2(vi[r][0], vi[r][1]);
  }
}

// ---------------------------------------------------------------------------
// GEMM: C[1024x8192] = A[1024x512] * B[512x8192], fp32 VALU.
// Block tile 128x128, 256 threads, per-thread 8x8 micro-tile.
// Wave-level 64x64 sub-tile: within a wave only 8 distinct As and 8 distinct
// Bs addresses per ds_read_b128 (stride-8-words -> 2-way bank alias = free).
// Register prefetch of next K-slab hides global latency under compute.
// ---------------------------------------------------------------------------
#define BM 128
#define BN 128
#define BK 16
#define LDA 132  // +4 pad
#define LDB 132  // +4 pad

__global__ __launch_bounds__(256, 2) void gemm_kernel(
    const float* __restrict__ A, const float* __restrict__ B,
    float* __restrict__ C) {
  __shared__ float As[BK][LDA];
  __shared__ float Bs[BK][LDB];

  const int tid = threadIdx.x;
  const int bm = blockIdx.y * BM;
  const int bn = blockIdx.x * BN;

  // wave-local 8x8 thread grid -> 64x64 wave sub-tile
  const int w  = tid >> 6;
  const int r8 = (tid >> 3) & 7;
  const int c8 = tid & 7;
  const int tm = ((w & 1) * 8 + r8) * 8;   // 0..120, row offset in tile
  const int tn = ((w >> 1) * 8 + c8) * 8;  // 0..120, col offset in tile

  // global load mapping
  const int a_m = tid >> 1;           // 0..127
  const int a_k = (tid & 1) * 8;      // 0 or 8
  const int b_k = tid >> 4;           // 0..15
  const int b_n = (tid & 15) * 8;     // 0..120

  const float* Ap = A + (size_t)(bm + a_m) * 512 + a_k;
  const float* Bp = B + (size_t)b_k * BATCH + bn + b_n;

  float acc[8][8] = {};

  // prefetch first slab
  float4 pa0 = *(const float4*)(Ap);
  float4 pa1 = *(const float4*)(Ap + 4);
  float4 pb0 = *(const float4*)(Bp);
  float4 pb1 = *(const float4*)(Bp + 4);

#pragma unroll 1
  for (int k0 = 0; k0 < 512; k0 += BK) {
    __syncthreads();
    // stage slab into LDS (A transposed to [k][m])
    As[a_k + 0][a_m] = pa0.x; As[a_k + 1][a_m] = pa0.y;
    As[a_k + 2][a_m] = pa0.z; As[a_k + 3][a_m] = pa0.w;
    As[a_k + 4][a_m] = pa1.x; As[a_k + 5][a_m] = pa1.y;
    As[a_k + 6][a_m] = pa1.z; As[a_k + 7][a_m] = pa1.w;
    *(float4*)&Bs[b_k][b_n] = pb0;
    *(float4*)&Bs[b_k][b_n + 4] = pb1;
    __syncthreads();

    // prefetch next slab (uniform branch)
    if (k0 + BK < 512) {
      pa0 = *(const float4*)(Ap + k0 + BK);
      pa1 = *(const float4*)(Ap + k0 + BK + 4);
      pb0 = *(const float4*)(Bp + (size_t)(k0 + BK) * BATCH);
      pb1 = *(const float4*)(Bp + (size_t)(k0 + BK) * BATCH + 4);
    }

#pragma unroll
    for (int kk = 0; kk < BK; ++kk) {
      float4 af0 = *(float4*)&As[kk][tm];
      float4 af1 = *(float4*)&As[kk][tm + 4];
      float4 bf0 = *(float4*)&Bs[kk][tn];
      float4 bf1 = *(float4*)&Bs[kk][tn + 4];
      float av[8] = {af0.x, af0.y, af0.z, af0.w, af1.x, af1.y, af1.z, af1.w};
      float bv[8] = {bf0.x, bf0.y, bf0.z, bf0.w, bf1.x, bf1.y, bf1.z, bf1.w};
#pragma unroll
      for (int i = 0; i < 8; ++i)
#pragma unroll
        for (int j = 0; j < 8; ++j)
          acc[i][j] += av[i] * bv[j];
    }
  }

  // epilogue
#pragma unroll
  for (int i = 0; i < 8; ++i) {
    float* cp = C + (size_t)(bm + tm + i) * BATCH + bn + tn;
    *(float4*)cp = make_float4(acc[i][0], acc[i][1], acc[i][2], acc[i][3]);
    *(float4*)(cp + 4) = make_float4(acc[i][4], acc[i][5], acc[i][6], acc[i][7]);
  }
}

extern "C" void kernel_launch(void* const* d_in, const int* in_sizes, int n_in,
                              void* d_out, int out_size, void* d_ws, size_t ws_size,
                              hipStream_t stream) {
  const float* x      = (const float*)d_in[0];
  const float* thetas = (const float*)d_in[1];
  const float* phis   = (const float*)d_in[2];
  const float* gammas = (const float*)d_in[3];
  const float* bse    = (const float*)d_in[4];
  const float* lse    = (const float*)d_in[5];
  // top/bottom/mask (d_in[6..8]) deterministic (Clements mesh) — derived analytically.

  float4* pp = (float4*)d_ws;                      // 131072 nodes * 32 B = 4 MB
  float*  T  = (float*)d_ws + 2 * 131072 * 4;      // 1024 x 512 fp32 = 2 MB

  precomp_kernel<<<512, 256, 0, stream>>>(thetas, phis, bse, lse, pp);

  // compose: 512 identity cols / NB=2 = 256 waves = 64 blocks
  compose_kernel<<<64, 256, 0, stream>>>(gammas, pp, T);

  // GEMM: C[1024x8192] = T[1024x512] * x[512x8192]
  dim3 grid(BATCH / BN, 1024 / BM);
  gemm_kernel<<<grid, 256, 0, stream>>>(T, x, (float*)d_out);
}

// Round 5
// 380.715 us; speedup vs baseline: 7.6605x; 1.8053x over previous
//
#include <hip/hip_runtime.h>
#include <math.h>

#define BATCH 8192
#define NROW 512
#define NCOL 512
#define MNODE 256

// ---------------------------------------------------------------------------
// Fused per-node 2x2 complex matrix: N = R * diag(e^{i th},1) * L * diag(e^{i ph},1)
// pp[2n+0] = (n11r, n11i, n12r, n12i); pp[2n+1] = (n21r, n21i, n22r, n22i)
// Apply: top' = n11*vt + n12*vb ; bot' = n21*vt + n22*vb   (verified rounds 1-4)
// ---------------------------------------------------------------------------
__global__ __launch_bounds__(256) void precomp_kernel(
    const float* __restrict__ thetas, const float* __restrict__ phis,
    const float* __restrict__ bse, const float* __restrict__ lse,
    float4* __restrict__ pp) {
  int n = blockIdx.x * 256 + threadIdx.x;
  float th = thetas[n], ph = phis[n];
  float e0 = bse[2 * n + 0], e1 = bse[2 * n + 1];
  float l0 = lse[2 * n + 0], l1 = lse[2 * n + 1];
  const float K = 0.16609640474436813f;  // log2(10)/20
  float ins0 = exp2f(l0 * K), ins1 = exp2f(l1 * K);
  const float PI4 = 0.7853981633974483f;
  float s0, c0, s1, c1, sp, cp, st, ct;
  sincosf(PI4 + e0, &s0, &c0);
  sincosf(PI4 + e1, &s1, &c1);
  sincosf(ph, &sp, &cp);
  sincosf(th, &st, &ct);
  float AL = ins0 * s0, C1L = c0, C2L = ins0 * c0, SL = s0;
  float AR = ins1 * s1, C1R = c1, C2R = ins1 * c1, SR = s1;
  float a11r = AL * cp,   a11i = AL * sp;
  float a12r = 0.f,       a12i = C1L;
  float a21r = -C2L * sp, a21i = C2L * cp;
  float a22r = SL,        a22i = 0.f;
  float b11r = a11r * ct - a11i * st, b11i = a11r * st + a11i * ct;
  float b12r = a12r * ct - a12i * st, b12i = a12r * st + a12i * ct;
  float n11r = AR * b11r - C1R * a21i;
  float n11i = AR * b11i + C1R * a21r;
  float n12r = AR * b12r - C1R * a22i;
  float n12i = AR * b12i + C1R * a22r;
  float n21r = -C2R * b11i + SR * a21r;
  float n21i =  C2R * b11r + SR * a21i;
  float n22r = -C2R * b12i + SR * a22r;
  float n22i =  C2R * b12r + SR * a22i;
  pp[2 * n + 0] = make_float4(n11r, n11i, n12r, n12i);
  pp[2 * n + 1] = make_float4(n21r, n21i, n22r, n22i);
}

// General complex 2x2 apply: 16 FMA-class ops.
__device__ __forceinline__ void proc_pair(float& vtr, float& vti, float& vbr, float& vbi,
                                          const float4 q0, const float4 q1) {
  float tr = q0.x * vtr - q0.y * vti + q0.z * vbr - q0.w * vbi;
  float ti = q0.x * vti + q0.y * vtr + q0.z * vbi + q0.w * vbr;
  float br = q1.x * vtr - q1.y * vti + q1.z * vbr - q1.w * vbi;
  float bi = q1.x * vti + q1.y * vtr + q1.z * vbi + q1.w * vbr;
  vtr = tr; vti = ti; vbr = br; vbi = bi;
}

// XOR swizzle on 16B-block index: spreads lane-strided b128 reads uniformly
// over all 8 bank groups. Involution: swz(swz(b)) == b.
__device__ __forceinline__ int swz(int b) { return b ^ ((b >> 3) & 7); }

// ---------------------------------------------------------------------------
// COMPOSE: T = Mesh(diag(e^{ig}) I), each wave sweeps ONE identity column.
// 4 waves/block share a double-buffered LDS stage of the per-column-pair node
// matrices (16 KB/pair, XOR-swizzled). Per iteration: issue next pair's global
// loads, ds_read this pair's matrices, compute (round-3-verified math, NB=1),
// ds_write the arrived fill, barrier. Cross-pair neighbor matrix comes straight
// from LDS (no shuffle). Output A[1024x512]: rows 0..511 T_re, 512..1023 T_im.
// ---------------------------------------------------------------------------
__global__ __launch_bounds__(256) void compose_kernel(
    const float* __restrict__ gammas, const float4* __restrict__ pp,
    float* __restrict__ T) {
  __shared__ float4 buf[2][1024];   // 32 KB: two column-pair param buffers
  __shared__ float ep[1024][5];     // 20 KB: epilogue transpose (padded)

  const int tid  = threadIdx.x;
  const int lane = tid & 63;
  const int w    = tid >> 6;              // wave in block (0..3)
  const int col  = blockIdx.x * 4 + w;    // identity column this wave builds

  // state: rows 8*lane .. 8*lane+7 of column `col`
  float vr[8], vi[8];
#pragma unroll
  for (int r = 0; r < 8; ++r) {
    const int row = lane * 8 + r;
    if (row == col) {
      float sg, cg;
      sincosf(gammas[row], &sg, &cg);
      vr[r] = cg; vi[r] = sg;
    } else {
      vr[r] = 0.f; vi[r] = 0.f;
    }
  }

  // prologue: fill buf[0] with column-pair 0 (blocks 0..1023 of pp)
  {
    const int sw = swz(tid);
#pragma unroll
    for (int k = 0; k < 4; ++k)
      buf[0][256 * k + sw] = pp[256 * k + tid];
  }
  __syncthreads();

#pragma unroll 1
  for (int p = 0; p < 256; ++p) {
    const int b = p & 1;

    // issue next pair's global loads early (latency hidden under compute)
    float4 f0, f1, f2, f3;
    if (p < 255) {
      const float4* src = pp + (size_t)(p + 1) * 1024;
      f0 = src[tid]; f1 = src[256 + tid]; f2 = src[512 + tid]; f3 = src[768 + tid];
    }

    // read this pair's node matrices from LDS (swizzled layout)
    float4 pe[8], po[8], pu1;
    {
      const int base = 8 * lane;
      const int l7 = lane & 7;
#pragma unroll
      for (int j = 0; j < 8; ++j) pe[j] = buf[b][base + (j ^ l7)];
#pragma unroll
      for (int j = 0; j < 8; ++j) po[j] = buf[b][512 + base + (j ^ l7)];
      const int lm = (lane == 0) ? 0 : lane - 1;
      pu1 = buf[b][512 + 8 * lm + (7 ^ (lm & 7))];  // neighbor node 4(l-1)+3 row1
    }

    // even column: pairs (2k,2k+1), node 4l+k
#pragma unroll
    for (int k = 0; k < 4; ++k)
      proc_pair(vr[2 * k], vi[2 * k], vr[2 * k + 1], vi[2 * k + 1],
                pe[2 * k], pe[2 * k + 1]);

    // odd column: in-lane pairs (2k+1,2k+2)
#pragma unroll
    for (int k = 0; k < 3; ++k)
      proc_pair(vr[2 * k + 1], vi[2 * k + 1], vr[2 * k + 2], vi[2 * k + 2],
                po[2 * k], po[2 * k + 1]);

    // cross pair, half-per-lane (round-3-verified); state via shuffles
    {
      float br = __shfl_down(vr[0], 1, 64);   // lane l+1's row0 (pre-update)
      float bi = __shfl_down(vi[0], 1, 64);
      float tu = __shfl_up(vr[7], 1, 64);     // lane l-1's old row7
      float tv = __shfl_up(vi[7], 1, 64);
      float nAr = po[6].x * vr[7] - po[6].y * vi[7] + po[6].z * br - po[6].w * bi;
      float nAi = po[6].x * vi[7] + po[6].y * vr[7] + po[6].z * bi + po[6].w * br;
      float nBr = pu1.x * tu - pu1.y * tv + pu1.z * vr[0] - pu1.w * vi[0];
      float nBi = pu1.x * tv + pu1.y * tu + pu1.z * vi[0] + pu1.w * vr[0];
      if (lane < 63) { vr[7] = nAr; vi[7] = nAi; }  // lane63 = masked node 255
      if (lane > 0)  { vr[0] = nBr; vi[0] = nBi; }  // lane0 row0 untouched
    }

    // stage the arrived fill into the other buffer
    if (p < 255) {
      const int sw = swz(tid);
      buf[1 - b][sw] = f0;
      buf[1 - b][256 + sw] = f1;
      buf[1 - b][512 + sw] = f2;
      buf[1 - b][768 + sw] = f3;
    }
    __syncthreads();
  }

  // epilogue: transpose through LDS for coalesced float4 stores.
  // ep[i][w]: i = row (0..511 re, 512..1023 im), w = wave = column within block.
#pragma unroll
  for (int r = 0; r < 8; ++r) {
    ep[lane * 8 + r][w] = vr[r];
    ep[512 + lane * 8 + r][w] = vi[r];
  }
  __syncthreads();
#pragma unroll
  for (int k = 0; k < 4; ++k) {
    const int i = k * 256 + tid;
    *(float4*)(T + (size_t)i * NROW + blockIdx.x * 4) =
        make_float4(ep[i][0], ep[i][1], ep[i][2], ep[i][3]);
  }
}

// ---------------------------------------------------------------------------
// GEMM: C[1024x8192] = A[1024x512] * B[512x8192], fp32 VALU. (unchanged r4)
// ---------------------------------------------------------------------------
#define BM 128
#define BN 128
#define BK 16
#define LDA 132
#define LDB 132

__global__ __launch_bounds__(256, 2) void gemm_kernel(
    const float* __restrict__ A, const float* __restrict__ B,
    float* __restrict__ C) {
  __shared__ float As[BK][LDA];
  __shared__ float Bs[BK][LDB];

  const int tid = threadIdx.x;
  const int bm = blockIdx.y * BM;
  const int bn = blockIdx.x * BN;

  const int w  = tid >> 6;
  const int r8 = (tid >> 3) & 7;
  const int c8 = tid & 7;
  const int tm = ((w & 1) * 8 + r8) * 8;
  const int tn = ((w >> 1) * 8 + c8) * 8;

  const int a_m = tid >> 1;
  const int a_k = (tid & 1) * 8;
  const int b_k = tid >> 4;
  const int b_n = (tid & 15) * 8;

  const float* Ap = A + (size_t)(bm + a_m) * 512 + a_k;
  const float* Bp = B + (size_t)b_k * BATCH + bn + b_n;

  float acc[8][8] = {};

  float4 pa0 = *(const float4*)(Ap);
  float4 pa1 = *(const float4*)(Ap + 4);
  float4 pb0 = *(const float4*)(Bp);
  float4 pb1 = *(const float4*)(Bp + 4);

#pragma unroll 1
  for (int k0 = 0; k0 < 512; k0 += BK) {
    __syncthreads();
    As[a_k + 0][a_m] = pa0.x; As[a_k + 1][a_m] = pa0.y;
    As[a_k + 2][a_m] = pa0.z; As[a_k + 3][a_m] = pa0.w;
    As[a_k + 4][a_m] = pa1.x; As[a_k + 5][a_m] = pa1.y;
    As[a_k + 6][a_m] = pa1.z; As[a_k + 7][a_m] = pa1.w;
    *(float4*)&Bs[b_k][b_n] = pb0;
    *(float4*)&Bs[b_k][b_n + 4] = pb1;
    __syncthreads();

    if (k0 + BK < 512) {
      pa0 = *(const float4*)(Ap + k0 + BK);
      pa1 = *(const float4*)(Ap + k0 + BK + 4);
      pb0 = *(const float4*)(Bp + (size_t)(k0 + BK) * BATCH);
      pb1 = *(const float4*)(Bp + (size_t)(k0 + BK) * BATCH + 4);
    }

#pragma unroll
    for (int kk = 0; kk < BK; ++kk) {
      float4 af0 = *(float4*)&As[kk][tm];
      float4 af1 = *(float4*)&As[kk][tm + 4];
      float4 bf0 = *(float4*)&Bs[kk][tn];
      float4 bf1 = *(float4*)&Bs[kk][tn + 4];
      float av[8] = {af0.x, af0.y, af0.z, af0.w, af1.x, af1.y, af1.z, af1.w};
      float bv[8] = {bf0.x, bf0.y, bf0.z, bf0.w, bf1.x, bf1.y, bf1.z, bf1.w};
#pragma unroll
      for (int i = 0; i < 8; ++i)
#pragma unroll
        for (int j = 0; j < 8; ++j)
          acc[i][j] += av[i] * bv[j];
    }
  }

#pragma unroll
  for (int i = 0; i < 8; ++i) {
    float* cp = C + (size_t)(bm + tm + i) * BATCH + bn + tn;
    *(float4*)cp = make_float4(acc[i][0], acc[i][1], acc[i][2], acc[i][3]);
    *(float4*)(cp + 4) = make_float4(acc[i][4], acc[i][5], acc[i][6], acc[i][7]);
  }
}

extern "C" void kernel_launch(void* const* d_in, const int* in_sizes, int n_in,
                              void* d_out, int out_size, void* d_ws, size_t ws_size,
                              hipStream_t stream) {
  const float* x      = (const float*)d_in[0];
  const float* thetas = (const float*)d_in[1];
  const float* phis   = (const float*)d_in[2];
  const float* gammas = (const float*)d_in[3];
  const float* bse    = (const float*)d_in[4];
  const float* lse    = (const float*)d_in[5];
  // top/bottom/mask (d_in[6..8]) deterministic (Clements mesh) — derived analytically.

  float4* pp = (float4*)d_ws;                      // 131072 nodes * 32 B = 4 MB
  float*  T  = (float*)d_ws + 2 * 131072 * 4;      // 1024 x 512 fp32 = 2 MB

  precomp_kernel<<<512, 256, 0, stream>>>(thetas, phis, bse, lse, pp);

  // compose: 512 identity cols, 1 per wave; 128 blocks x 4 waves
  compose_kernel<<<128, 256, 0, stream>>>(gammas, pp, T);

  // GEMM: C[1024x8192] = T[1024x512] * x[512x8192]
  dim3 grid(BATCH / BN, 1024 / BM);
  gemm_kernel<<<grid, 256, 0, stream>>>(T, x, (float*)d_out);
}